// Round 1
// baseline (332.537 us; speedup 1.0000x reference)
//
#include <hip/hip_runtime.h>
#include <hip/hip_bf16.h>

typedef __attribute__((ext_vector_type(8))) short short8;
typedef __attribute__((ext_vector_type(4))) float f32x4;

#define N_NODES 20000
#define N_EDGES 320000
#define NFEAT 512
#define NHID 1024

__device__ __forceinline__ float bf2f(unsigned short u) {
    union { unsigned int i; float f; } c; c.i = ((unsigned int)u) << 16; return c.f;
}
__device__ __forceinline__ unsigned short f2bf(float f) {
    union { float f; unsigned int i; } c; c.f = f;
    unsigned int x = c.i;
    return (unsigned short)((x + 0x7fffu + ((x >> 16) & 1u)) >> 16);
}

__device__ __forceinline__ void gload_lds16(const void* g, void* l) {
    __builtin_amdgcn_global_load_lds(
        (const __attribute__((address_space(1))) void*)g,
        (__attribute__((address_space(3))) void*)l, 16, 0, 0);
}

// ---------------- CSR build ----------------

__global__ void hist_kernel(const int* __restrict__ dst, int* __restrict__ deg, int E) {
    int e = blockIdx.x * 256 + threadIdx.x;
    if (e < E) atomicAdd(&deg[dst[e]], 1);
}

__global__ __launch_bounds__(1024) void scan_kernel(const int* __restrict__ deg,
                                                    int* __restrict__ row_ptr,
                                                    int* __restrict__ cursor, int n) {
    __shared__ int sdata[1024];
    const int t = threadIdx.x;
    constexpr int CH = 20;  // 1024*20 = 20480 >= 20000
    int base = t * CH;
    int local[CH];
    int sum = 0;
#pragma unroll
    for (int i = 0; i < CH; ++i) {
        int idx = base + i;
        int v = (idx < n) ? deg[idx] : 0;
        local[i] = sum;
        sum += v;
    }
    sdata[t] = sum;
    __syncthreads();
    for (int off = 1; off < 1024; off <<= 1) {
        int v = (t >= off) ? sdata[t - off] : 0;
        __syncthreads();
        sdata[t] += v;
        __syncthreads();
    }
    int prev = (t == 0) ? 0 : sdata[t - 1];
#pragma unroll
    for (int i = 0; i < CH; ++i) {
        int idx = base + i;
        if (idx < n) {
            int p = prev + local[i];
            row_ptr[idx] = p;
            cursor[idx]  = p;
        }
    }
    if (t == 1023) row_ptr[n] = sdata[1023];
}

__global__ void fill_kernel(const int* __restrict__ src, const int* __restrict__ dst,
                            const float* __restrict__ vals, int* __restrict__ cursor,
                            int* __restrict__ csr_src, float* __restrict__ csr_val, int E) {
    int e = blockIdx.x * 256 + threadIdx.x;
    if (e < E) {
        int d = dst[e];
        int pos = atomicAdd(&cursor[d], 1);
        csr_src[pos] = src[e];
        csr_val[pos] = vals[e];
    }
}

// ------------- W transpose + bf16 convert:  Wt[n][k] = W[k][n] -------------

__global__ void transpose_cvt(const float* __restrict__ W, unsigned short* __restrict__ Wt,
                              int K, int N) {
    __shared__ float tile[32][33];
    int ntx = N >> 5;
    int k0 = (blockIdx.x / ntx) << 5;
    int n0 = (blockIdx.x % ntx) << 5;
    int tx = threadIdx.x & 31, ty = threadIdx.x >> 5;  // ty 0..7
#pragma unroll
    for (int i = 0; i < 32; i += 8)
        tile[ty + i][tx] = W[(size_t)(k0 + ty + i) * N + n0 + tx];
    __syncthreads();
#pragma unroll
    for (int i = 0; i < 32; i += 8)
        Wt[(size_t)(n0 + ty + i) * K + k0 + tx] = f2bf(tile[tx][ty + i]);
}

// ------------- aggregation 1:  agg[d] = sum_e val_e * x[src_e]  (f32 in, bf16 out) -------------

__global__ void agg1_kernel(const float* __restrict__ x,
                            const int* __restrict__ csr_src,
                            const float* __restrict__ csr_val,
                            const int* __restrict__ row_ptr,
                            unsigned short* __restrict__ agg) {
    int d = blockIdx.x;
    int t = threadIdx.x;  // 0..127, 4 floats each -> 512
    int e0 = row_ptr[d], e1 = row_ptr[d + 1];
    f32x4 acc = {0.f, 0.f, 0.f, 0.f};
    for (int e = e0; e < e1; ++e) {
        int s = csr_src[e];
        float v = csr_val[e];
        f32x4 xv = ((const f32x4*)x)[(size_t)s * (NFEAT / 4) + t];
        acc += xv * v;
    }
    union { unsigned long long u; unsigned short s[4]; } o;
    o.s[0] = f2bf(acc[0]); o.s[1] = f2bf(acc[1]);
    o.s[2] = f2bf(acc[2]); o.s[3] = f2bf(acc[3]);
    ((unsigned long long*)agg)[(size_t)d * (NFEAT / 4) + t] = o.u;
}

// ------------- aggregation 2:  out[d] = b2 + sum_e val_e * s2[src_e]  (bf16 in, f32 out) -------------

__global__ void agg2_kernel(const unsigned short* __restrict__ s2,
                            const int* __restrict__ csr_src,
                            const float* __restrict__ csr_val,
                            const int* __restrict__ row_ptr,
                            const float* __restrict__ b2,
                            float* __restrict__ out) {
    int d = blockIdx.x;
    int t = threadIdx.x;  // 0..127, 4 elems each -> 512
    int e0 = row_ptr[d], e1 = row_ptr[d + 1];
    f32x4 acc = ((const f32x4*)b2)[t];
    for (int e = e0; e < e1; ++e) {
        int s = csr_src[e];
        float v = csr_val[e];
        unsigned long long w = ((const unsigned long long*)s2)[(size_t)s * (NFEAT / 4) + t];
        f32x4 xv;
        xv[0] = bf2f((unsigned short)(w));
        xv[1] = bf2f((unsigned short)(w >> 16));
        xv[2] = bf2f((unsigned short)(w >> 32));
        xv[3] = bf2f((unsigned short)(w >> 48));
        acc += xv * v;
    }
    ((f32x4*)out)[(size_t)d * (NFEAT / 4) + t] = acc;
}

// ------------- bf16 MFMA GEMM:  C[M,N] = A[M,K] * Bt[N,K]^T  (m97-style 128x128 tile) -------------
// EPI==1: C = bf16(dropout(relu(acc + bias)))   EPI==0: C = bf16(acc)

template <int EPI>
__global__ __launch_bounds__(256, 2) void gemm_bf16(
    const unsigned short* __restrict__ A,
    const unsigned short* __restrict__ Bt,
    unsigned short* __restrict__ C,
    int M, int N, int K,
    const float* __restrict__ bias,
    const float* __restrict__ u_drop) {
    __shared__ __align__(16) unsigned short lA[128 * 32];
    __shared__ __align__(16) unsigned short lB[128 * 32];

    const int nt = N >> 7;
    const int bm = blockIdx.x / nt;
    const int bn = blockIdx.x % nt;
    const int row0 = bm << 7;
    const int col0 = bn << 7;
    const int tid = threadIdx.x;
    const int wid = tid >> 6;
    const int lane = tid & 63;
    const int wr = wid >> 1, wc = wid & 1;  // wave computes 64x64 at (wr*64, wc*64)

    f32x4 acc[4][4] = {};

    const int srow = lane >> 2;          // row within 16-row chunk
    const int scol = (lane & 3) * 8;     // k element offset (8 bf16 = 16B)

    for (int k0 = 0; k0 < K; k0 += 32) {
#pragma unroll
        for (int c = 0; c < 2; ++c) {
            int r = c * 64 + wid * 16 + srow;          // 0..127
            unsigned loff = (unsigned)(c * 64 + wid * 16) * 32;  // ushort elems, wave-uniform
            int ga = row0 + r; if (ga >= M) ga = M - 1;
            gload_lds16(A + (size_t)ga * K + k0 + scol, &lA[loff]);
            int gb = col0 + r;                          // N tiles divide exactly
            gload_lds16(Bt + (size_t)gb * K + k0 + scol, &lB[loff]);
        }
        __syncthreads();

        short8 af[4], bf[4];
        const int kb = (lane >> 4) * 8;
#pragma unroll
        for (int m = 0; m < 4; ++m) {
            int rr = wr * 64 + m * 16 + (lane & 15);
            af[m] = *(const short8*)&lA[rr * 32 + kb];
        }
#pragma unroll
        for (int n = 0; n < 4; ++n) {
            int rr = wc * 64 + n * 16 + (lane & 15);
            bf[n] = *(const short8*)&lB[rr * 32 + kb];
        }
#pragma unroll
        for (int m = 0; m < 4; ++m)
#pragma unroll
            for (int n = 0; n < 4; ++n)
                acc[m][n] = __builtin_amdgcn_mfma_f32_16x16x32_bf16(af[m], bf[n], acc[m][n], 0, 0, 0);
        __syncthreads();
    }

    // epilogue: C/D layout col = lane&15, row = (lane>>4)*4 + j
    const int crow = (lane >> 4) * 4;
    const int ccol = lane & 15;
#pragma unroll
    for (int m = 0; m < 4; ++m) {
#pragma unroll
        for (int n = 0; n < 4; ++n) {
            int gr0 = row0 + wr * 64 + m * 16 + crow;
            int gc = col0 + wc * 64 + n * 16 + ccol;
#pragma unroll
            for (int j = 0; j < 4; ++j) {
                int gr = gr0 + j;
                if (gr < M) {
                    float v = acc[m][n][j];
                    if (EPI == 1) {
                        v += bias[gc];
                        v = v > 0.f ? v : 0.f;
                        float u = u_drop[(size_t)gr * N + gc];
                        v = (u > 0.5f) ? v * 2.0f : 0.0f;
                    }
                    C[(size_t)gr * N + gc] = f2bf(v);
                }
            }
        }
    }
}

// ---------------- launch ----------------

extern "C" void kernel_launch(void* const* d_in, const int* in_sizes, int n_in,
                              void* d_out, int out_size, void* d_ws, size_t ws_size,
                              hipStream_t stream) {
    const float* x        = (const float*)d_in[0];
    const float* W1       = (const float*)d_in[1];
    const float* b1       = (const float*)d_in[2];
    const float* W2       = (const float*)d_in[3];
    const float* b2       = (const float*)d_in[4];
    const float* adj_vals = (const float*)d_in[5];
    const float* u_drop   = (const float*)d_in[6];
    const int*   src      = (const int*)d_in[7];
    const int*   dst      = (const int*)d_in[8];
    float* out = (float*)d_out;

    char* p = (char*)d_ws;
    auto take = [&](size_t bytes) {
        char* q = p;
        p += (bytes + 255) & ~(size_t)255;
        return q;
    };
    int* deg        = (int*)take((size_t)N_NODES * 4);
    int* row_ptr    = (int*)take((size_t)(N_NODES + 1) * 4);
    int* cursor     = (int*)take((size_t)N_NODES * 4);
    int* csr_src    = (int*)take((size_t)N_EDGES * 4);
    float* csr_val  = (float*)take((size_t)N_EDGES * 4);
    unsigned short* w1t   = (unsigned short*)take((size_t)NFEAT * NHID * 2);
    unsigned short* w2t   = (unsigned short*)take((size_t)NFEAT * NHID * 2);
    unsigned short* agg1b = (unsigned short*)take((size_t)N_NODES * NFEAT * 2);
    unsigned short* hbuf  = (unsigned short*)take((size_t)N_NODES * NHID * 2);
    unsigned short* s2buf = (unsigned short*)take((size_t)N_NODES * NFEAT * 2);

    hipMemsetAsync(deg, 0, (size_t)N_NODES * 4, stream);
    hist_kernel<<<(N_EDGES + 255) / 256, 256, 0, stream>>>(dst, deg, N_EDGES);
    scan_kernel<<<1, 1024, 0, stream>>>(deg, row_ptr, cursor, N_NODES);
    fill_kernel<<<(N_EDGES + 255) / 256, 256, 0, stream>>>(src, dst, adj_vals, cursor,
                                                           csr_src, csr_val, N_EDGES);
    transpose_cvt<<<(NFEAT / 32) * (NHID / 32), 256, 0, stream>>>(W1, w1t, NFEAT, NHID);
    transpose_cvt<<<(NHID / 32) * (NFEAT / 32), 256, 0, stream>>>(W2, w2t, NHID, NFEAT);

    agg1_kernel<<<N_NODES, 128, 0, stream>>>(x, csr_src, csr_val, row_ptr, agg1b);

    const int mt = (N_NODES + 127) / 128;  // 157
    gemm_bf16<1><<<mt * (NHID / 128), 256, 0, stream>>>(agg1b, w1t, hbuf,
                                                        N_NODES, NHID, NFEAT, b1, u_drop);
    gemm_bf16<0><<<mt * (NFEAT / 128), 256, 0, stream>>>(hbuf, w2t, s2buf,
                                                         N_NODES, NFEAT, NHID, nullptr, nullptr);

    agg2_kernel<<<N_NODES, 128, 0, stream>>>(s2buf, csr_src, csr_val, row_ptr, b2, out);
}

// Round 2
// 330.678 us; speedup vs baseline: 1.0056x; 1.0056x over previous
//
#include <hip/hip_runtime.h>
#include <hip/hip_bf16.h>

typedef __attribute__((ext_vector_type(8))) short short8;
typedef __attribute__((ext_vector_type(4))) float f32x4;

#define N_NODES 20000
#define N_EDGES 320000
#define NFEAT 512
#define NHID 1024

__device__ __forceinline__ float bf2f(unsigned short u) {
    union { unsigned int i; float f; } c; c.i = ((unsigned int)u) << 16; return c.f;
}
__device__ __forceinline__ unsigned short f2bf(float f) {
    union { float f; unsigned int i; } c; c.f = f;
    unsigned int x = c.i;
    return (unsigned short)((x + 0x7fffu + ((x >> 16) & 1u)) >> 16);
}

__device__ __forceinline__ void gload_lds16(const void* g, void* l) {
    __builtin_amdgcn_global_load_lds(
        (const __attribute__((address_space(1))) void*)g,
        (__attribute__((address_space(3))) void*)l, 16, 0, 0);
}

// ---------------- CSR build ----------------

__global__ void hist_kernel(const int* __restrict__ dst, int* __restrict__ deg, int E) {
    int e = blockIdx.x * 256 + threadIdx.x;
    if (e < E) atomicAdd(&deg[dst[e]], 1);
}

__global__ __launch_bounds__(1024) void scan_kernel(const int* __restrict__ deg,
                                                    int* __restrict__ row_ptr,
                                                    int* __restrict__ cursor, int n) {
    __shared__ int sdata[1024];
    const int t = threadIdx.x;
    constexpr int CH = 20;  // 1024*20 = 20480 >= 20000
    int base = t * CH;
    int local[CH];
    int sum = 0;
#pragma unroll
    for (int i = 0; i < CH; ++i) {
        int idx = base + i;
        int v = (idx < n) ? deg[idx] : 0;
        local[i] = sum;
        sum += v;
    }
    sdata[t] = sum;
    __syncthreads();
    for (int off = 1; off < 1024; off <<= 1) {
        int v = (t >= off) ? sdata[t - off] : 0;
        __syncthreads();
        sdata[t] += v;
        __syncthreads();
    }
    int prev = (t == 0) ? 0 : sdata[t - 1];
#pragma unroll
    for (int i = 0; i < CH; ++i) {
        int idx = base + i;
        if (idx < n) {
            int p = prev + local[i];
            row_ptr[idx] = p;
            cursor[idx]  = p;
        }
    }
    if (t == 1023) row_ptr[n] = sdata[1023];
}

__global__ void fill_kernel(const int* __restrict__ src, const int* __restrict__ dst,
                            const float* __restrict__ vals, int* __restrict__ cursor,
                            int* __restrict__ csr_src, float* __restrict__ csr_val, int E) {
    int e = blockIdx.x * 256 + threadIdx.x;
    if (e < E) {
        int d = dst[e];
        int pos = atomicAdd(&cursor[d], 1);
        csr_src[pos] = src[e];
        csr_val[pos] = vals[e];
    }
}

// ------------- W transpose + bf16 convert:  Wt[n][k] = W[k][n] -------------

__global__ void transpose_cvt(const float* __restrict__ W, unsigned short* __restrict__ Wt,
                              int K, int N) {
    __shared__ float tile[32][33];
    int ntx = N >> 5;
    int k0 = (blockIdx.x / ntx) << 5;
    int n0 = (blockIdx.x % ntx) << 5;
    int tx = threadIdx.x & 31, ty = threadIdx.x >> 5;  // ty 0..7
#pragma unroll
    for (int i = 0; i < 32; i += 8)
        tile[ty + i][tx] = W[(size_t)(k0 + ty + i) * N + n0 + tx];
    __syncthreads();
#pragma unroll
    for (int i = 0; i < 32; i += 8)
        Wt[(size_t)(n0 + ty + i) * K + k0 + tx] = f2bf(tile[tx][ty + i]);
}

// ------------- aggregation 1:  agg[d] = sum_e val_e * x[src_e]  (f32 in, bf16 out) -------------

__global__ void agg1_kernel(const float* __restrict__ x,
                            const int* __restrict__ csr_src,
                            const float* __restrict__ csr_val,
                            const int* __restrict__ row_ptr,
                            unsigned short* __restrict__ agg) {
    int d = blockIdx.x;
    int t = threadIdx.x;  // 0..127, 4 floats each -> 512
    int e0 = row_ptr[d], e1 = row_ptr[d + 1];
    f32x4 acc = {0.f, 0.f, 0.f, 0.f};
    int e = e0;
    for (; e + 1 < e1; e += 2) {
        int s0 = csr_src[e], s1 = csr_src[e + 1];
        float v0 = csr_val[e], v1 = csr_val[e + 1];
        f32x4 x0 = ((const f32x4*)x)[(size_t)s0 * (NFEAT / 4) + t];
        f32x4 x1 = ((const f32x4*)x)[(size_t)s1 * (NFEAT / 4) + t];
        acc += x0 * v0;
        acc += x1 * v1;
    }
    if (e < e1) {
        int s0 = csr_src[e];
        float v0 = csr_val[e];
        f32x4 x0 = ((const f32x4*)x)[(size_t)s0 * (NFEAT / 4) + t];
        acc += x0 * v0;
    }
    union { unsigned long long u; unsigned short s[4]; } o;
    o.s[0] = f2bf(acc[0]); o.s[1] = f2bf(acc[1]);
    o.s[2] = f2bf(acc[2]); o.s[3] = f2bf(acc[3]);
    ((unsigned long long*)agg)[(size_t)d * (NFEAT / 4) + t] = o.u;
}

// ------------- aggregation 2:  out[d] = b2 + sum_e val_e * s2[src_e]  (bf16 in, f32 out) -------------

__device__ __forceinline__ f32x4 unpack4(unsigned long long w) {
    f32x4 r;
    r[0] = bf2f((unsigned short)(w));
    r[1] = bf2f((unsigned short)(w >> 16));
    r[2] = bf2f((unsigned short)(w >> 32));
    r[3] = bf2f((unsigned short)(w >> 48));
    return r;
}

__global__ void agg2_kernel(const unsigned short* __restrict__ s2,
                            const int* __restrict__ csr_src,
                            const float* __restrict__ csr_val,
                            const int* __restrict__ row_ptr,
                            const float* __restrict__ b2,
                            float* __restrict__ out) {
    int d = blockIdx.x;
    int t = threadIdx.x;  // 0..127, 4 elems each -> 512
    int e0 = row_ptr[d], e1 = row_ptr[d + 1];
    f32x4 acc = ((const f32x4*)b2)[t];
    int e = e0;
    for (; e + 1 < e1; e += 2) {
        int s0 = csr_src[e], s1 = csr_src[e + 1];
        float v0 = csr_val[e], v1 = csr_val[e + 1];
        unsigned long long w0 = ((const unsigned long long*)s2)[(size_t)s0 * (NFEAT / 4) + t];
        unsigned long long w1 = ((const unsigned long long*)s2)[(size_t)s1 * (NFEAT / 4) + t];
        acc += unpack4(w0) * v0;
        acc += unpack4(w1) * v1;
    }
    if (e < e1) {
        int s0 = csr_src[e];
        float v0 = csr_val[e];
        unsigned long long w0 = ((const unsigned long long*)s2)[(size_t)s0 * (NFEAT / 4) + t];
        acc += unpack4(w0) * v0;
    }
    ((f32x4*)out)[(size_t)d * (NFEAT / 4) + t] = acc;
}

// ------------- bf16 MFMA GEMM:  C[M,N] = A[M,K] * Bt[N,K]^T -------------
// 128x64 tile, BK=64, double-buffered LDS with prefetch (2-phase), XOR-swizzled LDS.
// EPI==1: C = bf16(dropout(relu(acc + bias)))   EPI==0: C = bf16(acc)

template <int EPI>
__global__ __launch_bounds__(256, 3) void gemm_bf16(
    const unsigned short* __restrict__ A,
    const unsigned short* __restrict__ Bt,
    unsigned short* __restrict__ C,
    int M, int N, int K,
    const float* __restrict__ bias,
    const float* __restrict__ u_drop) {
    // BK=64 -> row = 128B = 8 x 16B slots; swizzle slot ^= (row & 7)
    __shared__ __align__(16) unsigned short lA[2][128 * 64];
    __shared__ __align__(16) unsigned short lB[2][64 * 64];

    const int nt = N >> 6;          // tiles of 64 cols
    const int bm = blockIdx.x / nt;
    const int bn = blockIdx.x % nt;
    const int row0 = bm << 7;
    const int col0 = bn << 6;
    const int tid = threadIdx.x;
    const int wid = tid >> 6;
    const int lane = tid & 63;
    const int wr = wid >> 1, wc = wid & 1;  // wave computes 64x32 at (wr*64, wc*32)

    f32x4 acc[4][2] = {};

    // staging geometry: each gload covers 8 rows x 64 cols (64 lanes x 16B)
    const int srow = lane >> 3;                       // 0..7 row within chunk
    const int ksw  = (lane & 7) ^ srow;               // swizzled 16B slot for global src
    const int gA_koff = ksw * 8;                      // bf16 elems

    auto stage = [&](int buf, int k0) {
#pragma unroll
        for (int c = 0; c < 4; ++c) {                  // A: 128 rows
            int base = wid * 8 + c * 32;
            int ga = row0 + base + srow; if (ga >= M) ga = M - 1;
            gload_lds16(A + (size_t)ga * K + k0 + gA_koff, &lA[buf][base * 64]);
        }
#pragma unroll
        for (int c = 0; c < 2; ++c) {                  // B: 64 rows
            int base = wid * 8 + c * 32;
            int gb = col0 + base + srow;
            gload_lds16(Bt + (size_t)gb * K + k0 + gA_koff, &lB[buf][base * 64]);
        }
    };

    const int nkt = K >> 6;
    stage(0, 0);
    __syncthreads();
    int cur = 0;

    for (int kt = 0; kt < nkt; ++kt) {
        if (kt + 1 < nkt) stage(cur ^ 1, (kt + 1) << 6);

#pragma unroll
        for (int ks = 0; ks < 2; ++ks) {
            const int c16 = ks * 4 + (lane >> 4);      // 16B slot 0..7
            short8 af[4], bf[2];
#pragma unroll
            for (int m = 0; m < 4; ++m) {
                int ra = wr * 64 + m * 16 + (lane & 15);
                af[m] = *(const short8*)&lA[cur][ra * 64 + ((c16 ^ (ra & 7)) << 3)];
            }
#pragma unroll
            for (int n = 0; n < 2; ++n) {
                int rb = wc * 32 + n * 16 + (lane & 15);
                bf[n] = *(const short8*)&lB[cur][rb * 64 + ((c16 ^ (rb & 7)) << 3)];
            }
#pragma unroll
            for (int m = 0; m < 4; ++m)
#pragma unroll
                for (int n = 0; n < 2; ++n)
                    acc[m][n] = __builtin_amdgcn_mfma_f32_16x16x32_bf16(af[m], bf[n], acc[m][n], 0, 0, 0);
        }
        __syncthreads();
        cur ^= 1;
    }

    // epilogue: C/D layout col = lane&15, row = (lane>>4)*4 + j
    const int crow = (lane >> 4) * 4;
    const int ccol = lane & 15;
#pragma unroll
    for (int m = 0; m < 4; ++m) {
#pragma unroll
        for (int n = 0; n < 2; ++n) {
            int gr0 = row0 + wr * 64 + m * 16 + crow;
            int gc = col0 + wc * 32 + n * 16 + ccol;
#pragma unroll
            for (int j = 0; j < 4; ++j) {
                int gr = gr0 + j;
                if (gr < M) {
                    float v = acc[m][n][j];
                    if (EPI == 1) {
                        v += bias[gc];
                        v = v > 0.f ? v : 0.f;
                        float u = u_drop[(size_t)gr * N + gc];
                        v = (u > 0.5f) ? v * 2.0f : 0.0f;
                    }
                    C[(size_t)gr * N + gc] = f2bf(v);
                }
            }
        }
    }
}

// ---------------- launch ----------------

extern "C" void kernel_launch(void* const* d_in, const int* in_sizes, int n_in,
                              void* d_out, int out_size, void* d_ws, size_t ws_size,
                              hipStream_t stream) {
    const float* x        = (const float*)d_in[0];
    const float* W1       = (const float*)d_in[1];
    const float* b1       = (const float*)d_in[2];
    const float* W2       = (const float*)d_in[3];
    const float* b2       = (const float*)d_in[4];
    const float* adj_vals = (const float*)d_in[5];
    const float* u_drop   = (const float*)d_in[6];
    const int*   src      = (const int*)d_in[7];
    const int*   dst      = (const int*)d_in[8];
    float* out = (float*)d_out;

    char* p = (char*)d_ws;
    auto take = [&](size_t bytes) {
        char* q = p;
        p += (bytes + 255) & ~(size_t)255;
        return q;
    };
    int* deg        = (int*)take((size_t)N_NODES * 4);
    int* row_ptr    = (int*)take((size_t)(N_NODES + 1) * 4);
    int* cursor     = (int*)take((size_t)N_NODES * 4);
    int* csr_src    = (int*)take((size_t)N_EDGES * 4);
    float* csr_val  = (float*)take((size_t)N_EDGES * 4);
    unsigned short* w1t   = (unsigned short*)take((size_t)NFEAT * NHID * 2);
    unsigned short* w2t   = (unsigned short*)take((size_t)NFEAT * NHID * 2);
    unsigned short* agg1b = (unsigned short*)take((size_t)N_NODES * NFEAT * 2);
    unsigned short* hbuf  = (unsigned short*)take((size_t)N_NODES * NHID * 2);
    unsigned short* s2buf = (unsigned short*)take((size_t)N_NODES * NFEAT * 2);

    hipMemsetAsync(deg, 0, (size_t)N_NODES * 4, stream);
    hist_kernel<<<(N_EDGES + 255) / 256, 256, 0, stream>>>(dst, deg, N_EDGES);
    scan_kernel<<<1, 1024, 0, stream>>>(deg, row_ptr, cursor, N_NODES);
    fill_kernel<<<(N_EDGES + 255) / 256, 256, 0, stream>>>(src, dst, adj_vals, cursor,
                                                           csr_src, csr_val, N_EDGES);
    transpose_cvt<<<(NFEAT / 32) * (NHID / 32), 256, 0, stream>>>(W1, w1t, NFEAT, NHID);
    transpose_cvt<<<(NHID / 32) * (NFEAT / 32), 256, 0, stream>>>(W2, w2t, NHID, NFEAT);

    agg1_kernel<<<N_NODES, 128, 0, stream>>>(x, csr_src, csr_val, row_ptr, agg1b);

    const int mt = (N_NODES + 127) / 128;  // 157
    gemm_bf16<1><<<mt * (NHID / 64), 256, 0, stream>>>(agg1b, w1t, hbuf,
                                                       N_NODES, NHID, NFEAT, b1, u_drop);
    gemm_bf16<0><<<mt * (NFEAT / 64), 256, 0, stream>>>(hbuf, w2t, s2buf,
                                                        N_NODES, NFEAT, NHID, nullptr, nullptr);

    agg2_kernel<<<N_NODES, 128, 0, stream>>>(s2buf, csr_src, csr_val, row_ptr, b2, out);
}